// Round 2
// 371.628 us; speedup vs baseline: 1.1339x; 1.1339x over previous
//
#include <hip/hip_runtime.h>
#include <hip/hip_bf16.h>

// out[n,m] = t * ( dot(x_n, y_m) - 0.5*(||x_n||^2 + ||y_m||^2) )
// N=16384, M=4096, D=512, fp32 in/out.
// R4 = R3 with the double-buffer parity fix: prefetch for tile t+1 must land
// in buf ((t+1)&1), not unconditionally in buf1 (R3's `loff ^ 16384` bug --
// t=1 raced reads of buf1 with writes of buf1, and t=2/4/6 re-read stale
// tile0 data from buf0 -> absmax 196).
//
// Structure: 256x256 tile / 8 waves / BK=64 / double-buffered 128 KiB LDS,
// full-K-tile prefetch distance: issue next tile's 8 global_load_lds BEFORE
// the current tile's 64 MFMAs; single vmcnt(0)+barrier per 64 MFMAs.
// LDS keeps the conflict-free lane-linear sub-tile layout: the staged 16B
// chunk (row=l15, k-quad=lane>>4) lands at base+lane*16, exactly where the
// MFMA fragment ds_read_b128 for that lane reads it.

#define NN 16384
#define MM 4096
#define DD 512

using frag_ab = __attribute__((ext_vector_type(8))) short;  // 8 bf16 = 4 VGPRs
using floatx4 = __attribute__((ext_vector_type(4))) float;  // MFMA accumulator

using gas_ptr = const __attribute__((address_space(1))) void*;
using las_ptr = __attribute__((address_space(3))) void*;

__device__ __forceinline__ void async_copy16(const void* g, void* l) {
    __builtin_amdgcn_global_load_lds((gas_ptr)g, (las_ptr)l, 16, 0, 0);
}

__device__ __forceinline__ unsigned bf16rne(float f) {
    union { float f; unsigned u; } v; v.f = f;
    unsigned u = v.u + 0x7FFFu + ((v.u >> 16) & 1u);   // round-nearest-even
    return u >> 16;
}

__device__ __forceinline__ uint2 cvt4(float4 v) {
    uint2 r;
    r.x = bf16rne(v.x) | (bf16rne(v.y) << 16);
    r.y = bf16rne(v.z) | (bf16rne(v.w) << 16);
    return r;
}

// Fused prep for x AND y in one launch: one wave per row (64 lanes x 8 floats
// = 512 = D): sum-of-squares + bf16 copy. Blocks [0, NN/4) -> x, rest -> y.
__global__ void prep_all(const float* __restrict__ x, const float* __restrict__ y,
                         float* __restrict__ xsq, float* __restrict__ ysq,
                         unsigned short* __restrict__ xb, unsigned short* __restrict__ yb) {
    const int lane = threadIdx.x & 63;
    const int row  = blockIdx.x * 4 + (threadIdx.x >> 6);
    const float* src;
    unsigned short* db;
    float* ds;
    if (row < NN) {
        src = x + (size_t)row * DD; db = xb + (size_t)row * DD; ds = xsq + row;
    } else {
        const int r = row - NN;
        src = y + (size_t)r * DD; db = yb + (size_t)r * DD; ds = ysq + r;
    }
    const float* p = src + lane * 8;
    float4 a = *(const float4*)(p);
    float4 b = *(const float4*)(p + 4);
    uint2 lo = cvt4(a), hi = cvt4(b);
    *(uint4*)(db + lane * 8) = make_uint4(lo.x, lo.y, hi.x, hi.y);
    float s = a.x*a.x + a.y*a.y + a.z*a.z + a.w*a.w
            + b.x*b.x + b.y*b.y + b.z*b.z + b.w*b.w;
    #pragma unroll
    for (int off = 32; off > 0; off >>= 1) s += __shfl_xor(s, off);
    if (lane == 0) *ds = s;
}

// Legacy rowsq (fallback path, no bf16 copy).
__global__ void rowsq_kernel(const float* __restrict__ v, float* __restrict__ sq) {
    const int lane = threadIdx.x & 63;
    const int row  = blockIdx.x * 4 + (threadIdx.x >> 6);
    const float* p = v + (size_t)row * DD + lane * 8;
    float4 a = *(const float4*)(p);
    float4 b = *(const float4*)(p + 4);
    float s = a.x*a.x + a.y*a.y + a.z*a.z + a.w*a.w
            + b.x*b.x + b.y*b.y + b.z*b.z + b.w*b.w;
    #pragma unroll
    for (int off = 32; off > 0; off >>= 1) s += __shfl_xor(s, off);
    if (lane == 0) sq[row] = s;
}

// 256x256 tile, 8 waves (wx in {0,1} x-halves of 128 rows, wy in {0..3}
// y-quarters of 64 cols), BK=64, double-buffered LDS.
// LDS map (shorts): S[0..16383]=A buf0, S[16384..32767]=A buf1,
//                   S[32768..49151]=B buf0, S[49152..65535]=B buf1.
// Each buf = 32 sub-tiles of 512 shorts (1 KB): sub-tile id = rg*2 + kh,
// rg = 16-row group, kh = k-half (32 k's). Within sub-tile, element
// (row=l15, k=kh*32+quad*8+j) lives at short offset quad*128 + l15*8 + j,
// i.e. lane*8 — both the global_load_lds landing slot and the fragment read.
__global__ __launch_bounds__(512, 2) void protonet_gemm_256(
    const unsigned short* __restrict__ xb, const unsigned short* __restrict__ yb,
    const float* __restrict__ xsq, const float* __restrict__ ysq,
    const int* __restrict__ temp, float* __restrict__ out)
{
    __shared__ __align__(16) unsigned short S[65536];   // 128 KiB

    const int bn   = blockIdx.x;      // N/256 = 64
    const int bm   = blockIdx.y;      // M/256 = 16
    const int tid  = threadIdx.x;
    const int lane = tid & 63;
    const int wave = tid >> 6;
    const int wx   = wave >> 2;       // x half (128 rows)
    const int wy   = wave & 3;        // y quarter (64 cols)
    const int l15  = lane & 15;
    const int quad = lane >> 4;

    floatx4 acc[8][4] = {};

    // Staging assignment: wave w owns sub-tile copies s = w*8 .. w*8+7.
    // s < 32 -> A sub-tile s; s >= 32 -> B sub-tile s-32.
    const unsigned short* gsrc[8];
    int loff[8];                       // short offset into S (buf 0)
    #pragma unroll
    for (int c = 0; c < 8; ++c) {
        const int s  = wave * 8 + c;
        const int ss = s & 31;
        const int rg = ss >> 1;
        const int kh = ss & 1;
        const bool a_side = (s < 32);
        const unsigned short* base = a_side
            ? xb + ((size_t)(bn * 256 + rg * 16 + l15) * DD + kh * 32 + quad * 8)
            : yb + ((size_t)(bm * 256 + rg * 16 + l15) * DD + kh * 32 + quad * 8);
        gsrc[c] = base;
        loff[c] = (a_side ? 0 : 32768) + ss * 512;
    }

    // Prologue: stage tile 0 into buf 0, full drain once.
    #pragma unroll
    for (int c = 0; c < 8; ++c)
        async_copy16(gsrc[c], S + loff[c]);
    __syncthreads();

    for (int t = 0; t < 8; ++t) {
        const int koff = (t & 1) * 16384;

        // Prefetch tile t+1 into the OTHER buffer -- parity ((t+1)&1), the
        // R3 bug was an unconditional ^16384 here. Issued BEFORE the compute
        // so the end-of-tile vmcnt(0) drain has a full tile (~64 MFMAs) of
        // distance.
        if (t < 7) {
            const int k0n = (t + 1) * 64;
            const int pko = ((t + 1) & 1) * 16384;   // dest buffer offset
            #pragma unroll
            for (int c = 0; c < 8; ++c)
                async_copy16(gsrc[c] + k0n, S + (loff[c] + pko));
        }
        __builtin_amdgcn_sched_barrier(0);   // keep prefetch issue ahead of compute

        // B fragments for the whole K-tile: 8 x ds_read_b128.
        frag_ab b[4][2];
        #pragma unroll
        for (int fc = 0; fc < 4; ++fc)
            #pragma unroll
            for (int kh = 0; kh < 2; ++kh)
                b[fc][kh] = *(const frag_ab*)(S + 32768 + koff
                                              + ((wy * 4 + fc) * 2 + kh) * 512 + lane * 8);

        // Stream A in row-pairs: 4 phases x (4 ds_read_b128 + 16 MFMA).
        #pragma unroll
        for (int pr = 0; pr < 4; ++pr) {
            frag_ab a[2][2];
            #pragma unroll
            for (int i = 0; i < 2; ++i)
                #pragma unroll
                for (int kh = 0; kh < 2; ++kh)
                    a[i][kh] = *(const frag_ab*)(S + koff
                                  + ((wx * 8 + pr * 2 + i) * 2 + kh) * 512 + lane * 8);
            #pragma unroll
            for (int i = 0; i < 2; ++i)
                #pragma unroll
                for (int fc = 0; fc < 4; ++fc)
                    #pragma unroll
                    for (int kh = 0; kh < 2; ++kh)
                        acc[pr * 2 + i][fc] = __builtin_amdgcn_mfma_f32_16x16x32_bf16(
                            a[i][kh], b[fc][kh], acc[pr * 2 + i][fc], 0, 0, 0);
        }

        // Compiler emits s_waitcnt vmcnt(0) lgkmcnt(0) before s_barrier:
        // next tile's loads landed (all waves), this tile's reads consumed.
        __syncthreads();
    }

    // Epilogue: C/D layout col=lane&15 (m index), row=quad*4+reg (n index).
    const float tt = (float)(*temp);
    const int n_base = bn * 256 + wx * 128;
    const int m_base = bm * 256 + wy * 64;
    #pragma unroll
    for (int fr = 0; fr < 8; ++fr) {
        float xs[4];
        #pragma unroll
        for (int r = 0; r < 4; ++r) xs[r] = xsq[n_base + fr * 16 + quad * 4 + r];
        #pragma unroll
        for (int fc = 0; fc < 4; ++fc) {
            const int mcol = m_base + fc * 16 + l15;
            const float ys = ysq[mcol];
            #pragma unroll
            for (int r = 0; r < 4; ++r) {
                const int nrow = n_base + fr * 16 + quad * 4 + r;
                out[(size_t)nrow * MM + mcol] = tt * (acc[fr][fc][r] - 0.5f * (xs[r] + ys));
            }
        }
    }
}

// Fallback GEMM (R1): converts fp32->bf16 inside the K-loop. Used only if
// ws_size is too small for the bf16 copies.
__global__ __launch_bounds__(256) void protonet_gemm(
    const float* __restrict__ x, const float* __restrict__ y,
    const float* __restrict__ xsq, const float* __restrict__ ysq,
    const int* __restrict__ temp, float* __restrict__ out)
{
    __shared__ __align__(16) unsigned short As[128 * 32];
    __shared__ __align__(16) unsigned short Bs[128 * 32];

    const int bn   = blockIdx.x;
    const int bm   = blockIdx.y;
    const int tid  = threadIdx.x;
    const int lane = tid & 63;
    const int wave = tid >> 6;
    const int wn   = wave & 1;
    const int wm   = wave >> 1;
    const int l15  = lane & 15;
    const int quad = lane >> 4;

    floatx4 acc[4][4] = {};

    for (int k0 = 0; k0 < DD; k0 += 32) {
        #pragma unroll
        for (int i = 0; i < 4; ++i) {
            int c = tid + i * 256;
            int row = c >> 3, col4 = c & 7;
            float4 v = *(const float4*)(x + (size_t)(bn * 128 + row) * DD + k0 + col4 * 4);
            *(uint2*)(&As[row * 32 + col4 * 4]) = cvt4(v);
        }
        #pragma unroll
        for (int i = 0; i < 4; ++i) {
            int c = tid + i * 256;
            int row = c >> 3, col4 = c & 7;
            float4 v = *(const float4*)(y + (size_t)(bm * 128 + row) * DD + k0 + col4 * 4);
            *(uint2*)(&Bs[row * 32 + col4 * 4]) = cvt4(v);
        }
        __syncthreads();

        frag_ab a[4], b[4];
        #pragma unroll
        for (int t = 0; t < 4; ++t) {
            a[t] = *(const frag_ab*)(&As[(wn * 64 + t * 16 + l15) * 32 + quad * 8]);
            b[t] = *(const frag_ab*)(&Bs[(wm * 64 + t * 16 + l15) * 32 + quad * 8]);
        }
        #pragma unroll
        for (int tn = 0; tn < 4; ++tn)
            #pragma unroll
            for (int tm = 0; tm < 4; ++tm)
                acc[tn][tm] = __builtin_amdgcn_mfma_f32_16x16x32_bf16(
                    a[tn], b[tm], acc[tn][tm], 0, 0, 0);
        __syncthreads();
    }

    const float t = (float)(*temp);
    const int n_base = bn * 128 + wn * 64;
    const int m_base = bm * 128 + wm * 64;
    #pragma unroll
    for (int tn = 0; tn < 4; ++tn) {
        float xs[4];
        #pragma unroll
        for (int r = 0; r < 4; ++r) xs[r] = xsq[n_base + tn * 16 + quad * 4 + r];
        #pragma unroll
        for (int tm = 0; tm < 4; ++tm) {
            const int mcol = m_base + tm * 16 + l15;
            const float ys = ysq[mcol];
            #pragma unroll
            for (int r = 0; r < 4; ++r) {
                const int nrow = n_base + tn * 16 + quad * 4 + r;
                out[(size_t)nrow * MM + mcol] = t * (acc[tn][tm][r] - 0.5f * (xs[r] + ys));
            }
        }
    }
}

extern "C" void kernel_launch(void* const* d_in, const int* in_sizes, int n_in,
                              void* d_out, int out_size, void* d_ws, size_t ws_size,
                              hipStream_t stream) {
    const float* x    = (const float*)d_in[0];
    const float* y    = (const float*)d_in[1];
    const int*   temp = (const int*)d_in[2];
    float* out = (float*)d_out;

    float* xsq = (float*)d_ws;                       // 16384 f  (64 KB)
    float* ysq = xsq + NN;                           // 4096 f   (16 KB)
    unsigned short* xb = (unsigned short*)(ysq + MM);   // 16 MB
    unsigned short* yb = xb + (size_t)NN * DD;          // 4 MB

    const size_t need = (size_t)(NN + MM) * 4 + (size_t)(NN + MM) * DD * 2;

    if (ws_size >= need) {
        prep_all<<<(NN + MM) / 4, 256, 0, stream>>>(x, y, xsq, ysq, xb, yb);
        protonet_gemm_256<<<dim3(NN / 256, MM / 256), 512, 0, stream>>>(
            xb, yb, xsq, ysq, temp, out);
    } else {
        rowsq_kernel<<<NN / 4, 256, 0, stream>>>(x, xsq);
        rowsq_kernel<<<MM / 4, 256, 0, stream>>>(y, ysq);
        protonet_gemm<<<dim3(NN / 128, MM / 128), 256, 0, stream>>>(
            x, y, xsq, ysq, temp, out);
    }
}